// Round 4
// baseline (157.329 us; speedup 1.0000x reference)
//
#include <hip/hip_runtime.h>
#include <math.h>

// CellSegmentationLoss: fused focal + dice + boundary-BCE + IoU-aux loss.
// Inputs: d_in[0]=pred_masks (16*1*1024*1024 f32), d_in[1]=gt_masks (same),
//         d_in[2]=pred_iou (16 f32). Output: 1 f32 scalar.
//
// R4: register-allocator-proof deep prefetch. Each wave streams its private
// 4096-px slice through a private 4-slot LDS ring filled by
// global_load_lds (16B/lane, zero data VGPRs). No __syncthreads in the main
// loop (wave-private ring) -> no vmcnt(0) barrier drain; manual
// s_waitcnt vmcnt(6) keeps 3 slot-pairs permanently in flight.
// Steady-state per CU: 16 waves x 8 KB = 128 KB outstanding.

#define HW_PIX (1024 * 1024)
#define BATCH 16
constexpr int GRID = 1024;                               // 4 blocks/CU, one round
constexpr int BLOCKS_PER_IMG = GRID / BATCH;             // 64
constexpr int THREADS = 256;
constexpr int WAVES = THREADS / 64;                      // 4
constexpr int PIX_PER_BLOCK = HW_PIX / BLOCKS_PER_IMG;   // 16384
constexpr int PIX_PER_WAVE = PIX_PER_BLOCK / WAVES;      // 4096
constexpr int SLOT_PX = 256;                             // 1 KB per array per slot
constexpr int NSLOT = PIX_PER_WAVE / SLOT_PX;            // 16
constexpr int RING = 4;                                  // ring depth (slots)
constexpr int SLOT_BYTES = SLOT_PX * 4;                  // 1024
constexpr int WAVE_LDS = RING * 2 * SLOT_BYTES;          // 8 KB per wave

typedef const __attribute__((address_space(1))) unsigned int* gas_ptr;
typedef __attribute__((address_space(3))) unsigned int* las_ptr;

// s_waitcnt imm (gfx9 encoding): vmcnt[3:0] | expcnt<<4 | lgkmcnt<<8 | vmcnt_hi<<14
#define WAIT_VM6() { __builtin_amdgcn_s_waitcnt(0xF76); asm volatile("" ::: "memory"); }
#define WAIT_VM4() { __builtin_amdgcn_s_waitcnt(0xF74); asm volatile("" ::: "memory"); }
#define WAIT_VM2() { __builtin_amdgcn_s_waitcnt(0xF72); asm volatile("" ::: "memory"); }
#define WAIT_VM0() { __builtin_amdgcn_s_waitcnt(0xF70); asm volatile("" ::: "memory"); }

__global__ __launch_bounds__(THREADS) void
loss_partial(const float* __restrict__ x, const float* __restrict__ t,
             float* __restrict__ acc) {
  __shared__ char smem[WAVES * WAVE_LDS];                // 32 KB
  __shared__ float red[WAVES][7];

  const int b = blockIdx.x / BLOCKS_PER_IMG;             // batch of this block
  const int chunk = blockIdx.x % BLOCKS_PER_IMG;
  const int wave = threadIdx.x >> 6;
  const int lane = threadIdx.x & 63;
  const long wbase = (long)b * HW_PIX + (long)chunk * PIX_PER_BLOCK +
                     (long)wave * PIX_PER_WAVE;
  const float* gx = x + wbase;
  const float* gt = t + wbase;
  char* lds = smem + wave * WAVE_LDS;                    // wave-private ring

  float fsum = 0.f, csum = 0.f, isum = 0.f, psum = 0.f;
  unsigned tcnt = 0, bicnt = 0, bpcnt = 0;               // wave-uniform counts

  // One slot-pair DMA: 1 KB of x + 1 KB of t. LDS dest is wave-uniform base;
  // HW deposits lane's 16 B at base + lane*16. Global addr is per-lane.
  auto issue = [&](int slot) {
    const int s = slot & (RING - 1);
    const float* gxp = gx + slot * SLOT_PX + lane * 4;
    const float* gtp = gt + slot * SLOT_PX + lane * 4;
    char* lxp = lds + s * 2 * SLOT_BYTES;
    char* ltp = lxp + SLOT_BYTES;
    __builtin_amdgcn_global_load_lds((gas_ptr)(const void*)gxp,
                                     (las_ptr)(void*)lxp, 16, 0, 0);
    __builtin_amdgcn_global_load_lds((gas_ptr)(const void*)gtp,
                                     (las_ptr)(void*)ltp, 16, 0, 0);
  };

  auto compute = [&](int slot) {
    const int s = slot & (RING - 1);
    const float4 xv = *(const float4*)(lds + s * 2 * SLOT_BYTES + lane * 16);
    const float4 tv =
        *(const float4*)(lds + s * 2 * SLOT_BYTES + SLOT_BYTES + lane * 16);
    const float* xs = reinterpret_cast<const float*>(&xv);
    const float* ts = reinterpret_cast<const float*>(&tv);
#pragma unroll
    for (int j = 0; j < 4; ++j) {
      const float xx = xs[j];
      const float tt = ts[j];
      const float e = __expf(-fabsf(xx));                // exp(-|x|) in (0,1]
      const float sp = 1.0f + e;
      const float r = __builtin_amdgcn_rcpf(sp);
      const float p = (xx >= 0.0f) ? r : e * r;          // sigmoid(x)
      const float ce = fmaxf(xx, 0.0f) - xx * tt + __logf(sp);
      const float om = fmaf(tt, 1.0f - 2.0f * p, p);     // 1 - p_t
      const float at = 0.75f - 0.5f * tt;                // alpha_t
      fsum += at * ce * om * om;
      csum += ce;
      isum = fmaf(p, tt, isum);
      psum += p;
      const unsigned long long mt = __ballot(tt != 0.0f);
      const unsigned long long mb = __ballot(xx > 0.0f); // p>0.5 <=> x>0
      tcnt += (unsigned)__popcll(mt);
      bpcnt += (unsigned)__popcll(mb);
      bicnt += (unsigned)__popcll(mt & mb);
    }
  };

  // Fill the ring: 8 outstanding 1 KB DMAs per wave.
  issue(0); issue(1); issue(2); issue(3);
  // Steady state: wait for oldest pair only (vmcnt<=6), compute, refill.
#pragma unroll
  for (int j = 0; j < NSLOT - RING; ++j) {
    WAIT_VM6();
    compute(j);
    issue(j + RING);
  }
  // Drain.
  WAIT_VM6(); compute(NSLOT - 4);
  WAIT_VM4(); compute(NSLOT - 3);
  WAIT_VM2(); compute(NSLOT - 2);
  WAIT_VM0(); compute(NSLOT - 1);

  // Block reduction: wave shuffle -> LDS -> 7 per-block partials (no atomics).
  float vals[4] = {fsum, csum, isum, psum};
#pragma unroll
  for (int k = 0; k < 4; ++k) {
    float v = vals[k];
#pragma unroll
    for (int off = 32; off > 0; off >>= 1) v += __shfl_down(v, off);
    if (lane == 0) red[wave][k] = v;
  }
  if (lane == 0) {                   // ballot counts are already wave totals
    red[wave][4] = (float)tcnt;
    red[wave][5] = (float)bicnt;
    red[wave][6] = (float)bpcnt;
  }
  __syncthreads();
  if (threadIdx.x < 7) {
    acc[blockIdx.x * 7 + threadIdx.x] =
        red[0][threadIdx.x] + red[1][threadIdx.x] +
        red[2][threadIdx.x] + red[3][threadIdx.x];
  }
}

__global__ void loss_final(const float* __restrict__ acc,
                           const float* __restrict__ pred_iou,
                           float* __restrict__ out) {
  constexpr float SMOOTH = 1e-6f;
  __shared__ float fin[BATCH][7];
  const int tid = threadIdx.x;
  if (tid < BATCH * 7) {                     // sum 64 block-partials per (b,k)
    const int b = tid / 7, k = tid % 7;
    float s = 0.f;
    for (int i = 0; i < BLOCKS_PER_IMG; ++i)
      s += acc[(b * BLOCKS_PER_IMG + i) * 7 + k];
    fin[b][k] = s;
  }
  __syncthreads();
  if (tid < 64) {
    const int lane = tid;                    // lanes 0..15 carry batches
    float F = 0.f, C = 0.f, D = 0.f, Q = 0.f;
    if (lane < BATCH) {
      F = fin[lane][0];
      C = fin[lane][1];
      const float I = fin[lane][2], P = fin[lane][3], T = fin[lane][4],
                  BI = fin[lane][5], BP = fin[lane][6];
      D = (2.0f * I + SMOOTH) / (P + T + SMOOTH);        // dice term
      const float iou = (BI + SMOOTH) / (BP + T - BI + SMOOTH);
      const float d = pred_iou[lane] - iou;
      Q = d * d;
    }
#pragma unroll
    for (int off = 32; off > 0; off >>= 1) {
      F += __shfl_down(F, off);
      C += __shfl_down(C, off);
      D += __shfl_down(D, off);
      Q += __shfl_down(Q, off);
    }
    if (lane == 0) {
      const float invN = 1.0f / (float)((long)BATCH * HW_PIX);
      const float focal = F * invN;
      const float dice = 1.0f - D * (1.0f / (float)BATCH);
      const float half_boundary = C * invN;  // 0.5 * (2.0 * mean(ce))
      const float iou_loss = Q * (1.0f / (float)BATCH);
      out[0] = focal + dice + half_boundary + 0.1f * iou_loss;
    }
  }
}

extern "C" void kernel_launch(void* const* d_in, const int* in_sizes, int n_in,
                              void* d_out, int out_size, void* d_ws,
                              size_t ws_size, hipStream_t stream) {
  const float* x = (const float*)d_in[0];
  const float* t = (const float*)d_in[1];
  const float* piou = (const float*)d_in[2];
  float* acc = (float*)d_ws;                 // GRID*7 floats of block partials

  loss_partial<<<GRID, THREADS, 0, stream>>>(x, t, acc);
  loss_final<<<1, 128, 0, stream>>>(acc, piou, (float*)d_out);
}